// Round 8
// baseline (133.775 us; speedup 1.0000x reference)
//
#include <hip/hip_runtime.h>
#include <math.h>

#define TPB 256
#define TILE 128          // target points per LDS tile
#define PPT 2             // source points per thread
#define NSPLIT 32         // target splits (chunk = M/NSPLIT = 256 = 2 tiles)
#define NCOL 16           // source columns (N / (PPT*TPB))

// Per-column completion counters, each on its own 128B line to avoid the
// R4 pathology (17 counters in one line -> ~100us of serialized cross-XCD
// same-line RMWs). Zero-initialized at module load; self-reset every launch.
struct alignas(128) PadCnt { int v; int pad[31]; };
__device__ PadCnt g_colcnt[NCOL];
__device__ __attribute__((aligned(128))) int   g_fincnt;
__device__ __attribute__((aligned(128))) float g_colsum[NCOL];

// Single fused kernel (non-cooperative).
// Phase A: grid (NCOL, NSPLIT); block (bx,s): 512 source points (2/thread)
//   vs target chunk s (256 targets, 2 LDS tiles of float4{x,y,z,|t|^2}).
//   dist(s,t) = |s|^2 + (|t|^2 - 2 s.t): min/max of a = |t|^2 - 2 s.t tracked,
//   |s|^2 added at the end (monotone shift commutes with min/max).
//   part layout: [NSPLIT][N] float4 {min_start, max_start, min_end, max_end}.
// Column sync: 32nd finisher of column bx (device-scope padded counter +
//   fences) runs Phase B for that column's 512 points; 16th column finisher
//   sums the 16 column sums in fixed order (deterministic) -> mean.
__global__ __launch_bounds__(TPB, 4) void fused_reward(
    const float* __restrict__ source,
    const float* __restrict__ target,
    const float* __restrict__ label,
    const float* __restrict__ trans_m,
    const float* __restrict__ path_m,
    const float* __restrict__ path_maxprob_m,
    float4* __restrict__ part,
    float* __restrict__ out,
    int N, int M, int T)
{
    const int bx  = blockIdx.x;   // source column
    const int s   = blockIdx.y;   // target split
    const int tid = threadIdx.x;

    __shared__ float4 tgt[TILE];

    // ---- two source points per thread ----
    const int i0 = bx * (PPT * TPB) + tid;
    const int i1 = i0 + TPB;

    float sx0 = source[i0 * 3 + 0], sy0 = source[i0 * 3 + 1], sz0 = source[i0 * 3 + 2];
    float sx1 = source[i1 * 3 + 0], sy1 = source[i1 * 3 + 1], sz1 = source[i1 * 3 + 2];
    const long te = (long)(T - 1) * N * 3;
    const float ex0 = sx0 - trans_m[te + (long)i0 * 3 + 0];
    const float ey0 = sy0 - trans_m[te + (long)i0 * 3 + 1];
    const float ez0 = sz0 - trans_m[te + (long)i0 * 3 + 2];
    const float ex1 = sx1 - trans_m[te + (long)i1 * 3 + 0];
    const float ey1 = sy1 - trans_m[te + (long)i1 * 3 + 1];
    const float ez1 = sz1 - trans_m[te + (long)i1 * 3 + 2];

    const float ss0 = fmaf(sx0, sx0, fmaf(sy0, sy0, sz0 * sz0));
    const float ss1 = fmaf(sx1, sx1, fmaf(sy1, sy1, sz1 * sz1));
    const float ee0 = fmaf(ex0, ex0, fmaf(ey0, ey0, ez0 * ez0));
    const float ee1 = fmaf(ex1, ex1, fmaf(ey1, ey1, ez1 * ez1));
    sx0 *= -2.0f; sy0 *= -2.0f; sz0 *= -2.0f;
    sx1 *= -2.0f; sy1 *= -2.0f; sz1 *= -2.0f;
    const float fx0 = -2.0f * ex0, fy0 = -2.0f * ey0, fz0 = -2.0f * ez0;
    const float fx1 = -2.0f * ex1, fy1 = -2.0f * ey1, fz1 = -2.0f * ez1;

    float mn_s0 = 3.402823e38f, mx_s0 = -3.402823e38f;
    float mn_e0 = 3.402823e38f, mx_e0 = -3.402823e38f;
    float mn_s1 = 3.402823e38f, mx_s1 = -3.402823e38f;
    float mn_e1 = 3.402823e38f, mx_e1 = -3.402823e38f;

    const int chunk = M / NSPLIT;          // 256
    const int t_begin = s * chunk;

    for (int t0 = t_begin; t0 < t_begin + chunk; t0 += TILE) {
        __syncthreads();
        if (tid < TILE) {
            const long j = (long)t0 + tid;
            const float tx = target[j * 3 + 0];
            const float ty = target[j * 3 + 1];
            const float tz = target[j * 3 + 2];
            tgt[tid] = make_float4(tx, ty, tz, fmaf(tx, tx, fmaf(ty, ty, tz * tz)));
        }
        __syncthreads();

        #pragma unroll 8
        for (int j = 0; j < TILE; ++j) {
            const float4 t = tgt[j];
            float a0 = fmaf(sx0, t.x, t.w); a0 = fmaf(sy0, t.y, a0); a0 = fmaf(sz0, t.z, a0);
            mn_s0 = fminf(mn_s0, a0); mx_s0 = fmaxf(mx_s0, a0);
            float b0 = fmaf(fx0, t.x, t.w); b0 = fmaf(fy0, t.y, b0); b0 = fmaf(fz0, t.z, b0);
            mn_e0 = fminf(mn_e0, b0); mx_e0 = fmaxf(mx_e0, b0);
            float a1 = fmaf(sx1, t.x, t.w); a1 = fmaf(sy1, t.y, a1); a1 = fmaf(sz1, t.z, a1);
            mn_s1 = fminf(mn_s1, a1); mx_s1 = fmaxf(mx_s1, a1);
            float b1 = fmaf(fx1, t.x, t.w); b1 = fmaf(fy1, t.y, b1); b1 = fmaf(fz1, t.z, b1);
            mn_e1 = fminf(mn_e1, b1); mx_e1 = fmaxf(mx_e1, b1);
        }
    }

    part[(long)s * N + i0] = make_float4(mn_s0 + ss0, mx_s0 + ss0, mn_e0 + ee0, mx_e0 + ee0);
    part[(long)s * N + i1] = make_float4(mn_s1 + ss1, mx_s1 + ss1, mn_e1 + ee1, mx_e1 + ee1);

    // ---- column completion counter (own cache line per column) ----
    __threadfence();                    // publish partials device-wide
    __shared__ int s_old;
    if (tid == 0) s_old = atomicAdd(&g_colcnt[bx].v, 1);
    __syncthreads();
    if (s_old != NSPLIT - 1) return;    // not the last block of this column
    if (tid == 0) g_colcnt[bx].v = 0;   // self-reset (all adds complete)
    __threadfence();                    // acquire: order partial reads below

    // ---- Phase B: reduce this column's 512 points ----
    float v = 0.0f;
    #pragma unroll
    for (int pp = 0; pp < PPT; ++pp) {
        const int i = bx * (PPT * TPB) + pp * TPB + tid;
        float mins = 3.402823e38f, maxs = -3.402823e38f;
        float mine = 3.402823e38f, maxe = -3.402823e38f;
        #pragma unroll 4
        for (int sp = 0; sp < NSPLIT; ++sp) {
            const float4 q = part[(long)sp * N + i];
            mins = fminf(mins, q.x); maxs = fmaxf(maxs, q.y);
            mine = fminf(mine, q.z); maxe = fmaxf(maxe, q.w);
        }
        const float p = 0.002f, L0 = 0.4f, lam = 0.05f, gamma = 0.99f;
        const float loss_start = 0.99f * mins + 0.01f * maxs;
        const float loss_end   = 0.99f * mine + 0.01f * maxe;
        const float loss_dt    = loss_end - loss_start;
        const float d = fminf(loss_end / L0, 1.0f);
        const float l = expf(-label[i]);
        const float reward_end = -p * path_m[(long)(T - 1) * N + i]
                                 - (d + lam * l) * loss_dt;
        float R = 0.0f, L = 0.0f;
        for (int t = T - 1; t >= 0; --t) {
            const float r  = (t == T - 1) ? reward_end
                                          : (-p * path_m[(long)t * N + i]);
            const float lp = logf(path_maxprob_m[(long)t * N + i]);
            R = gamma * R + lp * (r + 0.02f);
            L -= R;
        }
        v += L / (float)T;
    }

    // block reduction (4 waves of 64), fixed order -> deterministic
    for (int off = 32; off > 0; off >>= 1) v += __shfl_down(v, off, 64);
    __shared__ float red[TPB / 64];
    const int wid = tid >> 6, lane = tid & 63;
    if (lane == 0) red[wid] = v;
    __syncthreads();
    if (tid == 0) {
        float csum = 0.0f;
        #pragma unroll
        for (int w = 0; w < TPB / 64; ++w) csum += red[w];
        g_colsum[bx] = csum;
        __threadfence();                // publish colsum
        const int o2 = atomicAdd(&g_fincnt, 1);
        if (o2 == NCOL - 1) {           // last column -> final deterministic sum
            g_fincnt = 0;               // self-reset
            __threadfence();            // acquire colsums
            float tot = 0.0f;
            for (int b = 0; b < NCOL; ++b)
                tot += ((volatile float*)g_colsum)[b];
            out[0] = tot / (float)N;
        }
    }
}

extern "C" void kernel_launch(void* const* d_in, const int* in_sizes, int n_in,
                              void* d_out, int out_size, void* d_ws, size_t ws_size,
                              hipStream_t stream) {
    const float* source = (const float*)d_in[0];
    const float* target = (const float*)d_in[1];
    const float* label  = (const float*)d_in[2];
    const float* trans  = (const float*)d_in[3];
    const float* path   = (const float*)d_in[4];
    const float* pmax   = (const float*)d_in[5];

    const int N = in_sizes[0] / 3;          // 8192
    const int M = in_sizes[1] / 3;          // 8192
    const int T = in_sizes[3] / (N * 3);    // 8

    float4* part = (float4*)d_ws;           // [NSPLIT][N] float4 (4 MB)

    fused_reward<<<dim3(NCOL, NSPLIT), TPB, 0, stream>>>(
        source, target, label, trans, path, pmax,
        part, (float*)d_out, N, M, T);
}